// Round 2
// baseline (320.457 us; speedup 1.0000x reference)
//
#include <hip/hip_runtime.h>
#include <hip/hip_bf16.h>

#define N_ATOMS 131072
#define DQ 256
#define H1 512
#define NTYPES 4
#define TILE_M 64
#define NPAD (N_ATOMS + NTYPES * TILE_M)       // 131328
#define BLOCKS_PER_TYPE 64

typedef __bf16 bf16x8 __attribute__((ext_vector_type(8)));
typedef float f32x16 __attribute__((ext_vector_type(16)));

__device__ __forceinline__ unsigned short f2bf(float f) {
  unsigned int u = __builtin_bit_cast(unsigned int, f);
  u += 0x7fffu + ((u >> 16) & 1u);   // RNE (inputs finite)
  return (unsigned short)(u >> 16);
}
__device__ __forceinline__ unsigned int pack2(float a, float b) {
  return (unsigned int)f2bf(a) | ((unsigned int)f2bf(b) << 16);
}
__device__ __forceinline__ float fast_tanh(float x) {
  float e = __expf(2.0f * x);
  return 1.0f - 2.0f * __builtin_amdgcn_rcpf(e + 1.0f);
}

// ---------------------------------------------------------------------------
// hist: perm[] = -1 + per-block histogram of Z
// ---------------------------------------------------------------------------
__global__ __launch_bounds__(256) void hist_kernel(
    const int* __restrict__ Z, int* __restrict__ perm,
    int* __restrict__ blockcounts)
{
  const int b = blockIdx.x, tid = threadIdx.x;
  const int gid = b * 256 + tid;
  for (int i = gid; i < NPAD; i += 512 * 256) perm[i] = -1;
  __shared__ int lc[NTYPES];
  if (tid < NTYPES) lc[tid] = 0;
  __syncthreads();
  atomicAdd(&lc[Z[gid]], 1);     // grid 512*256 == N exactly
  __syncthreads();
  if (tid < NTYPES) blockcounts[b * NTYPES + tid] = lc[tid];
}

// ---------------------------------------------------------------------------
// w0s: W0 fp32 [t][k][n] -> bf16 chunks [t][kg2=k/8][n][8k], via LDS tile so
// both global read and global write are coalesced (old version did stride-2KB
// scalar reads).
// ---------------------------------------------------------------------------
__global__ __launch_bounds__(256) void w0s_kernel(
    const float* __restrict__ W0, unsigned short* __restrict__ W0s)
{
  __shared__ __align__(16) unsigned short S[64][72];   // [n][k], pad to 72
  const int b = blockIdx.x;
  const int nb = b & 7, kb = (b >> 3) & 3, t = b >> 5;
  const int tid = threadIdx.x;
  const int kl = tid >> 4, nl = (tid & 15) * 4;
#pragma unroll
  for (int r = 0; r < 4; ++r) {
    const int k = r * 16 + kl;
    const float4 v = *(const float4*)&W0[((size_t)(t * DQ + kb * 64 + k)) * H1 + nb * 64 + nl];
    S[nl + 0][k] = f2bf(v.x);
    S[nl + 1][k] = f2bf(v.y);
    S[nl + 2][k] = f2bf(v.z);
    S[nl + 3][k] = f2bf(v.w);
  }
  __syncthreads();
#pragma unroll
  for (int r = 0; r < 2; ++r) {
    const int c = r * 256 + tid;
    const int n = c & 63, kg2l = c >> 6;
    const uint4 v = *(const uint4*)&S[n][kg2l * 8];
    ((uint4*)W0s)[(size_t)(t * 32 + kb * 8 + kg2l) * H1 + nb * 64 + n] = v;
  }
}

// ---------------------------------------------------------------------------
// scan: per-block histograms -> padded (x64) segment offsets + cursors
// ---------------------------------------------------------------------------
__global__ __launch_bounds__(256) void scan_kernel(
    const int* __restrict__ blockcounts, int* __restrict__ padded_off,
    int* __restrict__ cursors)
{
  __shared__ int sums[NTYPES];
  const int tid = threadIdx.x;
  if (tid < NTYPES) sums[tid] = 0;
  __syncthreads();
  const int t = tid & 3;
  int acc = 0;
  for (int b = tid >> 2; b < 512; b += 64) acc += blockcounts[b * 4 + t];
  atomicAdd(&sums[t], acc);
  __syncthreads();
  if (tid == 0) {
    int off = 0;
#pragma unroll
    for (int i = 0; i < NTYPES; ++i) {
      padded_off[i] = off;
      cursors[i] = off;
      off += (sums[i] + TILE_M - 1) & ~(TILE_M - 1);
    }
    padded_off[NTYPES] = off;
  }
}

// ---------------------------------------------------------------------------
// scatter: block-aggregated type binning
// ---------------------------------------------------------------------------
__global__ __launch_bounds__(256) void scatter_kernel(
    const int* __restrict__ Z, int* __restrict__ cursors, int* __restrict__ perm)
{
  __shared__ int lc[NTYPES], lbase[NTYPES];
  const int tid = threadIdx.x;
  const int gid = blockIdx.x * 256 + tid;
  if (tid < NTYPES) lc[tid] = 0;
  __syncthreads();
  const int t  = Z[gid];
  const int my = atomicAdd(&lc[t], 1);
  __syncthreads();
  if (tid < NTYPES) lbase[tid] = lc[tid] ? atomicAdd(&cursors[tid], lc[tid]) : 0;
  __syncthreads();
  perm[lbase[t] + my] = gid;
}

// ---------------------------------------------------------------------------
// gemm: persistent single-type blocks. 8 waves x (64 rows x 64 cols) tile.
// B (type slice of W0s) lives in 128 VGPRs per lane, loaded ONCE per block.
// K-loop = ds_read + MFMA only. A double-buffered in LDS; next tile's q
// loads issued before the current K-loop (overlap HBM with MFMA).
// ---------------------------------------------------------------------------
__device__ __forceinline__ void load_tile(const float* __restrict__ q,
    const int* __restrict__ perm, int row0, int w, int l, float4 ld[8]) {
  int atom = perm[row0 + l];
  if (atom < 0) atom = 0;
  const float* src = q + (size_t)atom * DQ + w * 32;
#pragma unroll
  for (int i = 0; i < 8; ++i) ld[i] = *(const float4*)(src + i * 4);
}

__device__ __forceinline__ void store_tile(unsigned short* Abuf, int w, int l,
                                           const float4 ld[8]) {
#pragma unroll
  for (int i = 0; i < 4; ++i) {
    uint4 v;
    v.x = pack2(ld[2 * i].x, ld[2 * i].y);
    v.y = pack2(ld[2 * i].z, ld[2 * i].w);
    v.z = pack2(ld[2 * i + 1].x, ld[2 * i + 1].y);
    v.w = pack2(ld[2 * i + 1].z, ld[2 * i + 1].w);
    *(uint4*)&Abuf[((w * 4 + i) * 64 + l) * 8] = v;
  }
}

__global__ __launch_bounds__(512, 2) void gemm_kernel(
    const float* __restrict__ q, const int* __restrict__ perm,
    const int* __restrict__ padded_off, const unsigned short* __restrict__ W0s,
    const float* __restrict__ b0, const float* __restrict__ W1,
    const float* __restrict__ b1p, float* __restrict__ out)
{
  __shared__ __align__(16) unsigned short A[2][32 * 64 * 8];  // 2 x 32 KB
  __shared__ float Fws[8][64];

  const int tid = threadIdx.x;
  const int w = tid >> 6, l = tid & 63;
  const int half = l >> 5, ln = l & 31;

  const int t = blockIdx.x >> 6;
  const int bslot = blockIdx.x & 63;
  const int seg0 = padded_off[t];
  const int ntiles = (padded_off[t + 1] - seg0) >> 6;
  if (bslot >= ntiles) return;

  const int colbase = w * 64;

  // per-type epilogue constants
  float b0v[2], w1v[2];
#pragma unroll
  for (int nt = 0; nt < 2; ++nt) {
    const int c = colbase + nt * 32 + ln;
    b0v[nt] = b0[t * H1 + c];
    w1v[nt] = W1[t * H1 + c];
  }
  const float b1 = b1p[0];

  // ---- B slice -> registers (once per block) ----
  const unsigned short* Bt = W0s + (size_t)t * (DQ * H1);
  bf16x8 Bf[16][2];
#pragma unroll
  for (int ks = 0; ks < 16; ++ks) {
    const int kg2 = ks * 2 + half;
#pragma unroll
    for (int nt = 0; nt < 2; ++nt)
      Bf[ks][nt] = *(const bf16x8*)(Bt + ((size_t)kg2 * H1 + colbase + nt * 32 + ln) * 8);
  }

  // ---- prolog: stage first tile ----
  int j = bslot;
  int row0 = seg0 + (j << 6);
  {
    float4 ld[8];
    load_tile(q, perm, row0, w, l, ld);
    store_tile(A[0], w, l, ld);
  }
  __syncthreads();
  int p = 0;

  for (;;) {
    const int jn = j + BLOCKS_PER_TYPE;
    const bool have_next = jn < ntiles;
    const int row0n = seg0 + (jn << 6);

    // issue next tile's q loads now; they overlap the K-loop + epilogue
    float4 ld[8];
    if (have_next) load_tile(q, perm, row0n, w, l, ld);

    // ---- K-loop: LDS + registers only ----
    const unsigned short* Acur = A[p];
    f32x16 acc[2][2];
#pragma unroll
    for (int mt = 0; mt < 2; ++mt)
#pragma unroll
      for (int nt = 0; nt < 2; ++nt) acc[mt][nt] = (f32x16)0.0f;

#pragma unroll
    for (int ks = 0; ks < 16; ++ks) {
      const int kg2 = ks * 2 + half;
      const bf16x8 a0 = *(const bf16x8*)&Acur[(kg2 * 64 + ln) * 8];
      const bf16x8 a1 = *(const bf16x8*)&Acur[(kg2 * 64 + 32 + ln) * 8];
      acc[0][0] = __builtin_amdgcn_mfma_f32_32x32x16_bf16(a0, Bf[ks][0], acc[0][0], 0, 0, 0);
      acc[1][0] = __builtin_amdgcn_mfma_f32_32x32x16_bf16(a1, Bf[ks][0], acc[1][0], 0, 0, 0);
      acc[0][1] = __builtin_amdgcn_mfma_f32_32x32x16_bf16(a0, Bf[ks][1], acc[0][1], 0, 0, 0);
      acc[1][1] = __builtin_amdgcn_mfma_f32_32x32x16_bf16(a1, Bf[ks][1], acc[1][1], 0, 0, 0);
    }

    // ---- epilogue: tanh + W1-dot, butterfly over 32-lane half ----
#pragma unroll
    for (int mt = 0; mt < 2; ++mt) {
#pragma unroll
      for (int r = 0; r < 16; ++r) {
        float s = w1v[0] * fast_tanh(acc[mt][0][r] + b0v[0])
                + w1v[1] * fast_tanh(acc[mt][1][r] + b0v[1]);
        s += __shfl_xor(s, 1);
        s += __shfl_xor(s, 2);
        s += __shfl_xor(s, 4);
        s += __shfl_xor(s, 8);
        s += __shfl_xor(s, 16);
        if (ln == 0)
          Fws[w][mt * 32 + (r & 3) + 8 * (r >> 2) + 4 * half] = s;
      }
    }
    __syncthreads();

    if (tid < TILE_M) {
      const int atom = perm[row0 + tid];
      if (atom >= 0) {
        float f = b1;
#pragma unroll
        for (int ww = 0; ww < 8; ++ww) f += Fws[ww][tid];
        out[atom] = f;
      }
    }

    if (!have_next) break;

    store_tile(A[1 - p], w, l, ld);   // waits vmcnt via ld use
    __syncthreads();
    p ^= 1;
    j = jn;
    row0 = row0n;
  }
}

extern "C" void kernel_launch(void* const* d_in, const int* in_sizes, int n_in,
                              void* d_out, int out_size, void* d_ws, size_t ws_size,
                              hipStream_t stream) {
  const float* q  = (const float*)d_in[0];
  const int*   Z  = (const int*)d_in[1];
  const float* W0 = (const float*)d_in[2];
  const float* b0 = (const float*)d_in[3];
  const float* W1 = (const float*)d_in[4];
  const float* b1 = (const float*)d_in[5];
  float* out = (float*)d_out;

  char* ws = (char*)d_ws;
  int* blockcounts = (int*)(ws);                          // 8 KB
  int* padded_off  = (int*)(ws + 8192);                   // 5 ints
  int* cursors     = (int*)(ws + 8192 + 32);              // 4 ints
  int* perm        = (int*)(ws + 8192 + 64);              // NPAD ints
  unsigned short* W0s = (unsigned short*)(ws + 8192 + 64 + (size_t)NPAD * 4); // 1 MB

  hipLaunchKernelGGL(hist_kernel,    dim3(512), dim3(256), 0, stream, Z, perm, blockcounts);
  hipLaunchKernelGGL(w0s_kernel,     dim3(128), dim3(256), 0, stream, W0, W0s);
  hipLaunchKernelGGL(scan_kernel,    dim3(1),   dim3(256), 0, stream, blockcounts, padded_off, cursors);
  hipLaunchKernelGGL(scatter_kernel, dim3(512), dim3(256), 0, stream, Z, cursors, perm);
  hipLaunchKernelGGL(gemm_kernel,    dim3(NTYPES * BLOCKS_PER_TYPE), dim3(512), 0, stream,
                     q, perm, padded_off, W0s, b0, W1, b1, out);
}

// Round 3
// 292.577 us; speedup vs baseline: 1.0953x; 1.0953x over previous
//
#include <hip/hip_runtime.h>
#include <hip/hip_bf16.h>

#define N_ATOMS 131072
#define DQ 256
#define H1 512
#define NTYPES 4
#define TILE_M 64
#define NPAD (N_ATOMS + NTYPES * TILE_M)       // 131328
#define BLOCKS_PER_TYPE 64
#define ROWPAD 65                              // 64 rows + 1 pad: LDS bank spread

typedef __bf16 bf16x8 __attribute__((ext_vector_type(8)));
typedef float f32x16 __attribute__((ext_vector_type(16)));

// RNE pack of two fp32 into one u32 of two bf16 (low = a). 5 VALU ops.
__device__ __forceinline__ unsigned int pack2(float a, float b) {
  unsigned int ua = __builtin_bit_cast(unsigned int, a);
  unsigned int ub = __builtin_bit_cast(unsigned int, b);
  ua += 0x7fffu + ((ua >> 16) & 1u);
  ub += 0x7fffu + ((ub >> 16) & 1u);
  return __builtin_amdgcn_perm(ub, ua, 0x07060302);  // [a_hi16 | b_hi16<<16]
}
__device__ __forceinline__ unsigned short f2bf(float f) {
  unsigned int u = __builtin_bit_cast(unsigned int, f);
  u += 0x7fffu + ((u >> 16) & 1u);
  return (unsigned short)(u >> 16);
}
__device__ __forceinline__ float fast_tanh(float x) {
  float e = __expf(2.0f * x);
  return 1.0f - 2.0f * __builtin_amdgcn_rcpf(e + 1.0f);
}
// butterfly stage on the VALU pipe (DPP) instead of ds_swizzle
template <int CTRL>
__device__ __forceinline__ float dpp_add(float s) {
  int v = __builtin_amdgcn_mov_dpp(__builtin_bit_cast(int, s), CTRL, 0xF, 0xF, true);
  return s + __builtin_bit_cast(float, v);
}

// ---------------------------------------------------------------------------
// prep: perm init + per-block Z histogram; blocks < 128 also transpose W0
// fp32 [t][k][n] -> bf16 chunks [t][kg2][n][8k] (coalesced via LDS tile).
// ---------------------------------------------------------------------------
__global__ __launch_bounds__(256) void prep_kernel(
    const float* __restrict__ W0, const int* __restrict__ Z,
    unsigned short* __restrict__ W0s, int* __restrict__ perm,
    int* __restrict__ blockcounts)
{
  __shared__ int lc[NTYPES];
  __shared__ __align__(16) unsigned short S[64][72];
  const int b = blockIdx.x, tid = threadIdx.x;
  const int gid = b * 256 + tid;

  for (int i = gid; i < NPAD; i += 512 * 256) perm[i] = -1;
  if (tid < NTYPES) lc[tid] = 0;
  __syncthreads();
  atomicAdd(&lc[Z[gid]], 1);     // grid 512*256 == N exactly

  if (b < 128) {                 // block-uniform branch: inner syncs legal
    const int nb = b & 7, kb = (b >> 3) & 3, t = b >> 5;
    const int kl = tid >> 4, nl = (tid & 15) * 4;
#pragma unroll
    for (int r = 0; r < 4; ++r) {
      const int k = r * 16 + kl;
      const float4 v = *(const float4*)&W0[((size_t)(t * DQ + kb * 64 + k)) * H1 + nb * 64 + nl];
      S[nl + 0][k] = f2bf(v.x);
      S[nl + 1][k] = f2bf(v.y);
      S[nl + 2][k] = f2bf(v.z);
      S[nl + 3][k] = f2bf(v.w);
    }
    __syncthreads();
#pragma unroll
    for (int r = 0; r < 2; ++r) {
      const int c = r * 256 + tid;
      const int n = c & 63, kg2l = c >> 6;
      const uint4 v = *(const uint4*)&S[n][kg2l * 8];
      ((uint4*)W0s)[(size_t)(t * 32 + kb * 8 + kg2l) * H1 + nb * 64 + n] = v;
    }
  }
  __syncthreads();
  if (tid < NTYPES) blockcounts[b * NTYPES + tid] = lc[tid];
}

__global__ __launch_bounds__(256) void scan_kernel(
    const int* __restrict__ blockcounts, int* __restrict__ padded_off,
    int* __restrict__ cursors)
{
  __shared__ int sums[NTYPES];
  const int tid = threadIdx.x;
  if (tid < NTYPES) sums[tid] = 0;
  __syncthreads();
  const int t = tid & 3;
  int acc = 0;
  for (int b = tid >> 2; b < 512; b += 64) acc += blockcounts[b * 4 + t];
  atomicAdd(&sums[t], acc);
  __syncthreads();
  if (tid == 0) {
    int off = 0;
#pragma unroll
    for (int i = 0; i < NTYPES; ++i) {
      padded_off[i] = off;
      cursors[i] = off;
      off += (sums[i] + TILE_M - 1) & ~(TILE_M - 1);
    }
    padded_off[NTYPES] = off;
  }
}

__global__ __launch_bounds__(256) void scatter_kernel(
    const int* __restrict__ Z, int* __restrict__ cursors, int* __restrict__ perm)
{
  __shared__ int lc[NTYPES], lbase[NTYPES];
  const int tid = threadIdx.x;
  const int gid = blockIdx.x * 256 + tid;
  if (tid < NTYPES) lc[tid] = 0;
  __syncthreads();
  const int t  = Z[gid];
  const int my = atomicAdd(&lc[t], 1);
  __syncthreads();
  if (tid < NTYPES) lbase[tid] = lc[tid] ? atomicAdd(&cursors[tid], lc[tid]) : 0;
  __syncthreads();
  perm[lbase[t] + my] = gid;
}

// ---------------------------------------------------------------------------
// gemm: persistent per-type blocks (256 blocks, 8 waves). B slice in VGPRs,
// loaded once. A staging: ONE WAVE INSTR = ONE FULL q ROW (coalesced 1 KB);
// pack fp32->bf16 once at stage time into padded MFMA-layout LDS.
// K-loop: ds_read_b128 + MFMA only. Register double-buffer of next tile.
// ---------------------------------------------------------------------------
__global__ __launch_bounds__(512, 2) void gemm_kernel(
    const float* __restrict__ q, const int* __restrict__ perm,
    const int* __restrict__ padded_off, const unsigned short* __restrict__ W0s,
    const float* __restrict__ b0, const float* __restrict__ W1,
    const float* __restrict__ b1p, float* __restrict__ out)
{
  __shared__ __align__(16) unsigned short A[2][32 * ROWPAD * 8];  // 2 x 32.5 KB
  __shared__ float Fws[8][64];

  const int tid = threadIdx.x;
  const int w = tid >> 6, l = tid & 63;
  const int half = l >> 5, ln = l & 31;

  const int t = blockIdx.x >> 6;
  const int bslot = blockIdx.x & 63;
  const int seg0 = padded_off[t];
  const int ntiles = (padded_off[t + 1] - seg0) >> 6;
  if (bslot >= ntiles) return;

  const int colbase = w * 64;

  float b0v[2], w1v[2];
#pragma unroll
  for (int nt = 0; nt < 2; ++nt) {
    const int c = colbase + nt * 32 + ln;
    b0v[nt] = b0[t * H1 + c];
    w1v[nt] = W1[t * H1 + c];
  }
  const float b1 = b1p[0];

  // ---- B slice -> registers, once (coalesced 16 B/lane from L2) ----
  const unsigned short* Bt = W0s + (size_t)t * (DQ * H1);
  bf16x8 Bf[16][2];
#pragma unroll
  for (int ks = 0; ks < 16; ++ks) {
    const int kg2 = ks * 2 + half;
#pragma unroll
    for (int nt = 0; nt < 2; ++nt)
      Bf[ks][nt] = *(const bf16x8*)(Bt + ((size_t)kg2 * H1 + colbase + nt * 32 + ln) * 8);
  }

  // ---- prolog: stage first tile (coalesced row loads, pack, ds_write) ----
  int j = bslot;
  int row0 = seg0 + (j << 6);
#pragma unroll
  for (int i = 0; i < 8; ++i) {
    int a = perm[row0 + w * 8 + i];
    if (a < 0) a = 0;
    const float4 v = *(const float4*)(q + (size_t)a * DQ + l * 4);
    uint2 u;
    u.x = pack2(v.x, v.y);
    u.y = pack2(v.z, v.w);
    *(uint2*)&A[0][((l >> 1) * ROWPAD + w * 8 + i) * 8 + (l & 1) * 4] = u;
  }
  __syncthreads();
  int p = 0;

  for (;;) {
    const int jn = j + BLOCKS_PER_TYPE;
    const bool have_next = jn < ntiles;
    const int rbase = have_next ? seg0 + (jn << 6) : row0;

    // prefetch next tile rows (coalesced: 1 row per instruction)
    float4 ld[8];
#pragma unroll
    for (int i = 0; i < 8; ++i) {
      int a = perm[rbase + w * 8 + i];
      if (a < 0) a = 0;
      ld[i] = *(const float4*)(q + (size_t)a * DQ + l * 4);
    }
    __builtin_amdgcn_sched_barrier(0);   // pin load issue before the K-loop

    // ---- K-loop: LDS + registers only ----
    const unsigned short* Acur = A[p];
    f32x16 acc[2][2];
#pragma unroll
    for (int mt = 0; mt < 2; ++mt)
#pragma unroll
      for (int nt = 0; nt < 2; ++nt) acc[mt][nt] = (f32x16)0.0f;

#pragma unroll
    for (int ks = 0; ks < 16; ++ks) {
      const int kg2 = ks * 2 + half;
      const bf16x8 a0 = *(const bf16x8*)&Acur[(kg2 * ROWPAD + ln) * 8];
      const bf16x8 a1 = *(const bf16x8*)&Acur[(kg2 * ROWPAD + 32 + ln) * 8];
      acc[0][0] = __builtin_amdgcn_mfma_f32_32x32x16_bf16(a0, Bf[ks][0], acc[0][0], 0, 0, 0);
      acc[1][0] = __builtin_amdgcn_mfma_f32_32x32x16_bf16(a1, Bf[ks][0], acc[1][0], 0, 0, 0);
      acc[0][1] = __builtin_amdgcn_mfma_f32_32x32x16_bf16(a0, Bf[ks][1], acc[0][1], 0, 0, 0);
      acc[1][1] = __builtin_amdgcn_mfma_f32_32x32x16_bf16(a1, Bf[ks][1], acc[1][1], 0, 0, 0);
    }

    // ---- epilogue: tanh + W1-dot; butterfly (3 DPP + 2 swizzle stages) ----
#pragma unroll
    for (int mt = 0; mt < 2; ++mt) {
#pragma unroll
      for (int r = 0; r < 16; ++r) {
        float s = w1v[0] * fast_tanh(acc[mt][0][r] + b0v[0])
                + w1v[1] * fast_tanh(acc[mt][1][r] + b0v[1]);
        s = dpp_add<0xB1>(s);           // xor 1 (quad_perm [1,0,3,2])
        s = dpp_add<0x4E>(s);           // xor 2 (quad_perm [2,3,0,1])
        s += __shfl_xor(s, 4);          // xor 4
        s = dpp_add<0x128>(s);          // xor 8 (row_ror:8)
        s += __shfl_xor(s, 16);         // xor 16
        if (ln == 0)
          Fws[w][mt * 32 + (r & 3) + 8 * (r >> 2) + 4 * half] = s;
      }
    }
    __syncthreads();

    if (tid < TILE_M) {
      const int atom = perm[row0 + tid];
      if (atom >= 0) {
        float f = b1;
#pragma unroll
        for (int ww = 0; ww < 8; ++ww) f += Fws[ww][tid];
        out[atom] = f;
      }
    }

    // stage prefetched rows into the other buffer (unconditional: always used
    // unless we break, so the loads above can't be sunk by liveness)
#pragma unroll
    for (int i = 0; i < 8; ++i) {
      uint2 u;
      u.x = pack2(ld[i].x, ld[i].y);
      u.y = pack2(ld[i].z, ld[i].w);
      *(uint2*)&A[1 - p][((l >> 1) * ROWPAD + w * 8 + i) * 8 + (l & 1) * 4] = u;
    }

    if (!have_next) break;
    __syncthreads();
    p ^= 1;
    j = jn;
    row0 = rbase;
  }
}

extern "C" void kernel_launch(void* const* d_in, const int* in_sizes, int n_in,
                              void* d_out, int out_size, void* d_ws, size_t ws_size,
                              hipStream_t stream) {
  const float* q  = (const float*)d_in[0];
  const int*   Z  = (const int*)d_in[1];
  const float* W0 = (const float*)d_in[2];
  const float* b0 = (const float*)d_in[3];
  const float* W1 = (const float*)d_in[4];
  const float* b1 = (const float*)d_in[5];
  float* out = (float*)d_out;

  char* ws = (char*)d_ws;
  int* blockcounts = (int*)(ws);                          // 8 KB
  int* padded_off  = (int*)(ws + 8192);                   // 5 ints
  int* cursors     = (int*)(ws + 8192 + 32);              // 4 ints
  int* perm        = (int*)(ws + 8192 + 64);              // NPAD ints
  unsigned short* W0s = (unsigned short*)(ws + 8192 + 64 + (size_t)NPAD * 4); // 1 MB

  hipLaunchKernelGGL(prep_kernel,    dim3(512), dim3(256), 0, stream, W0, Z, W0s, perm, blockcounts);
  hipLaunchKernelGGL(scan_kernel,    dim3(1),   dim3(256), 0, stream, blockcounts, padded_off, cursors);
  hipLaunchKernelGGL(scatter_kernel, dim3(512), dim3(256), 0, stream, Z, cursors, perm);
  hipLaunchKernelGGL(gemm_kernel,    dim3(NTYPES * BLOCKS_PER_TYPE), dim3(512), 0, stream,
                     q, perm, padded_off, W0s, b0, W1, b1, out);
}